// Round 1
// baseline (1306.746 us; speedup 1.0000x reference)
//
#include <hip/hip_runtime.h>
#include <math.h>

#define N_NODES 50000
#define N_EDGES 600000
#define D_IN 256
#define D_GNN 128

// ---------------------------------------------------------------------------
// GEMM: out[n][d] = sum_k x[n][k] * W[k][d]   (x: [N,256], W: [256,128])
// FINAL=false: out = y  (projection for neighbor aggregation)
// FINAL=true : out[n][d] = acc + b_l[d] + agg[n][d]/max(cnt[n],1)  (in-place:
//              'out' already holds agg from the scatter kernel)
// Tile: 32 nodes/block, 256 threads. Thread (tx=t&63, ty=t>>6) computes
// dims {tx, tx+64} for nodes {ty*8 .. ty*8+7}. x tile staged in LDS, read
// back as broadcast float4 (4 k's per read) -> FMA-bound inner loop.
// ---------------------------------------------------------------------------
template <bool FINAL>
__global__ __launch_bounds__(256) void gemm_kernel(
    const float* __restrict__ x, const float* __restrict__ W,
    float* __restrict__ out, const float* __restrict__ b_l,
    const float* __restrict__ cnt) {
  __shared__ float4 xs[32 * 64];  // 32 nodes x 256 k (as 64 float4) = 32 KiB
  const int t = threadIdx.x;
  const int n0 = blockIdx.x * 32;

  // cooperative staging: coalesced float4 loads (row = node, col = k/4)
  for (int i = t; i < 32 * 64; i += 256) {
    int row = i >> 6, col = i & 63;
    int gn = n0 + row;
    if (gn >= N_NODES) gn = N_NODES - 1;  // clamp; results discarded on store
    xs[i] = ((const float4*)x)[gn * 64 + col];
  }
  __syncthreads();

  const int tx = t & 63, ty = t >> 6;
  const int d0 = tx, d1 = tx + 64;

  float acc0[8], acc1[8];
#pragma unroll
  for (int i = 0; i < 8; i++) { acc0[i] = 0.f; acc1[i] = 0.f; }

  for (int k4 = 0; k4 < 64; k4++) {
    const int k = k4 * 4;
    // 8 coalesced W loads (256B/wave each, L1/L2-resident)
    float wa0 = W[(k + 0) * D_GNN + d0], wb0 = W[(k + 0) * D_GNN + d1];
    float wa1 = W[(k + 1) * D_GNN + d0], wb1 = W[(k + 1) * D_GNN + d1];
    float wa2 = W[(k + 2) * D_GNN + d0], wb2 = W[(k + 2) * D_GNN + d1];
    float wa3 = W[(k + 3) * D_GNN + d0], wb3 = W[(k + 3) * D_GNN + d1];
#pragma unroll
    for (int i = 0; i < 8; i++) {
      float4 xv = xs[(ty * 8 + i) * 64 + k4];  // broadcast within wave
      acc0[i] += xv.x * wa0 + xv.y * wa1 + xv.z * wa2 + xv.w * wa3;
      acc1[i] += xv.x * wb0 + xv.y * wb1 + xv.z * wb2 + xv.w * wb3;
    }
  }

#pragma unroll
  for (int i = 0; i < 8; i++) {
    int gn = n0 + ty * 8 + i;
    if (gn < N_NODES) {
      if (FINAL) {
        float ic = 1.f / fmaxf(cnt[gn], 1.f);
        float a0 = out[gn * D_GNN + d0];  // agg (scattered projected sums)
        float a1 = out[gn * D_GNN + d1];
        out[gn * D_GNN + d0] = acc0[i] + b_l[d0] + a0 * ic;
        out[gn * D_GNN + d1] = acc1[i] + b_l[d1] + a1 * ic;
      } else {
        out[gn * D_GNN + d0] = acc0[i];
        out[gn * D_GNN + d1] = acc1[i];
      }
    }
  }
}

// ---------------------------------------------------------------------------
// Edge scatter: 32 lanes per edge, each lane handles 4 dims (float4 gather of
// y[src], 4 f32 atomicAdds into agg[dst]). Lane 0 bumps the degree count.
// ---------------------------------------------------------------------------
__global__ __launch_bounds__(256) void scatter_kernel(
    const int* __restrict__ ei, const float* __restrict__ y,
    float* __restrict__ agg, float* __restrict__ cnt) {
  const int gid = blockIdx.x * 256 + threadIdx.x;
  const int e = gid >> 5;
  const int j = gid & 31;
  if (e >= N_EDGES) return;
  const int src = ei[e];
  const int dst = ei[N_EDGES + e];
  float4 v = ((const float4*)y)[src * 32 + j];
  float* p = agg + dst * D_GNN + j * 4;
  atomicAdd(p + 0, v.x);
  atomicAdd(p + 1, v.y);
  atomicAdd(p + 2, v.z);
  atomicAdd(p + 3, v.w);
  if (j == 0) atomicAdd(cnt + dst, 1.0f);
}

// ---------------------------------------------------------------------------
// Head: pred[n] = sigmoid(dot(h[n], W_fc) + b_fc). One wave per node.
// ---------------------------------------------------------------------------
__global__ __launch_bounds__(256) void pred_kernel(
    const float* __restrict__ h, const float* __restrict__ Wfc,
    const float* __restrict__ bfc, float* __restrict__ pred) {
  const int node = (blockIdx.x * 256 + threadIdx.x) >> 6;
  const int lane = threadIdx.x & 63;
  if (node >= N_NODES) return;
  float s = h[node * D_GNN + lane] * Wfc[lane] +
            h[node * D_GNN + 64 + lane] * Wfc[64 + lane];
#pragma unroll
  for (int off = 32; off > 0; off >>= 1) s += __shfl_down(s, off);
  if (lane == 0) pred[node] = 1.f / (1.f + expf(-(s + bfc[0])));
}

extern "C" void kernel_launch(void* const* d_in, const int* in_sizes, int n_in,
                              void* d_out, int out_size, void* d_ws,
                              size_t ws_size, hipStream_t stream) {
  const float* x   = (const float*)d_in[0];
  const int*   ei  = (const int*)d_in[1];   // [2, E] flat: src row then dst row
  const float* Wl  = (const float*)d_in[2];
  const float* bl  = (const float*)d_in[3];
  const float* Wr  = (const float*)d_in[4];
  const float* Wfc = (const float*)d_in[5];
  const float* bfc = (const float*)d_in[6];

  float* out  = (float*)d_out;
  float* h    = out;                       // [N, 128], doubles as agg buffer
  float* pred = out + (size_t)N_NODES * D_GNN;

  float* y   = (float*)d_ws;               // [N, 128] projected features
  float* cnt = y + (size_t)N_NODES * D_GNN;

  // zero the agg accumulator (h region of d_out) and degree counts
  hipMemsetAsync(h, 0, (size_t)N_NODES * D_GNN * sizeof(float), stream);
  hipMemsetAsync(cnt, 0, (size_t)N_NODES * sizeof(float), stream);

  const int gemm_blocks = (N_NODES + 31) / 32;  // 1563
  gemm_kernel<false><<<gemm_blocks, 256, 0, stream>>>(x, Wl, y, nullptr, nullptr);

  const int scat_blocks = (N_EDGES * 32) / 256;  // 75000
  scatter_kernel<<<scat_blocks, 256, 0, stream>>>(ei, y, h, cnt);

  gemm_kernel<true><<<gemm_blocks, 256, 0, stream>>>(x, Wr, h, bl, cnt);

  pred_kernel<<<(N_NODES * 64) / 256, 256, 0, stream>>>(h, Wfc, bfc, pred);
}

// Round 2
// 461.643 us; speedup vs baseline: 2.8306x; 2.8306x over previous
//
#include <hip/hip_runtime.h>
#include <math.h>

#define N_NODES 50000
#define N_EDGES 600000
#define D_IN 256
#define D_GNN 128

// ---------------------------------------------------------------------------
// GEMM: out[n][d] = sum_k x[n][k] * W[k][d]   (x: [N,256], W: [256,128])
// FINAL=false: out = y  (projection y = x@W_l for neighbor aggregation)
// FINAL=true : h = acc + b_l[d] + mean[n][d]  (mean already in 'out' from the
//              gather kernel, updated in-place), plus fused pred epilogue:
//              pred[n] = sigmoid(dot(h[n], W_fc) + b_fc) via wave shuffle
//              (each wave owns nodes ty*8..ty*8+7 across all 128 dims).
// ---------------------------------------------------------------------------
template <bool FINAL>
__global__ __launch_bounds__(256) void gemm_kernel(
    const float* __restrict__ x, const float* __restrict__ W,
    float* __restrict__ out, const float* __restrict__ b_l,
    const float* __restrict__ Wfc, const float* __restrict__ bfc,
    float* __restrict__ pred) {
  __shared__ float4 xs[32 * 64];  // 32 nodes x 256 k (as 64 float4) = 32 KiB
  const int t = threadIdx.x;
  const int n0 = blockIdx.x * 32;

  for (int i = t; i < 32 * 64; i += 256) {
    int row = i >> 6, col = i & 63;
    int gn = n0 + row;
    if (gn >= N_NODES) gn = N_NODES - 1;  // clamp; results discarded on store
    xs[i] = ((const float4*)x)[gn * 64 + col];
  }
  __syncthreads();

  const int tx = t & 63, ty = t >> 6;
  const int d0 = tx, d1 = tx + 64;

  float acc0[8], acc1[8];
#pragma unroll
  for (int i = 0; i < 8; i++) { acc0[i] = 0.f; acc1[i] = 0.f; }

  for (int k4 = 0; k4 < 64; k4++) {
    const int k = k4 * 4;
    float wa0 = W[(k + 0) * D_GNN + d0], wb0 = W[(k + 0) * D_GNN + d1];
    float wa1 = W[(k + 1) * D_GNN + d0], wb1 = W[(k + 1) * D_GNN + d1];
    float wa2 = W[(k + 2) * D_GNN + d0], wb2 = W[(k + 2) * D_GNN + d1];
    float wa3 = W[(k + 3) * D_GNN + d0], wb3 = W[(k + 3) * D_GNN + d1];
#pragma unroll
    for (int i = 0; i < 8; i++) {
      float4 xv = xs[(ty * 8 + i) * 64 + k4];  // broadcast within wave
      acc0[i] += xv.x * wa0 + xv.y * wa1 + xv.z * wa2 + xv.w * wa3;
      acc1[i] += xv.x * wb0 + xv.y * wb1 + xv.z * wb2 + xv.w * wb3;
    }
  }

#pragma unroll
  for (int i = 0; i < 8; i++) {
    int gn = n0 + ty * 8 + i;
    if (gn >= N_NODES) continue;
    if (FINAL) {
      float h0 = acc0[i] + b_l[d0] + out[gn * D_GNN + d0];  // out holds mean
      float h1 = acc1[i] + b_l[d1] + out[gn * D_GNN + d1];
      out[gn * D_GNN + d0] = h0;
      out[gn * D_GNN + d1] = h1;
      float s = h0 * Wfc[d0] + h1 * Wfc[d1];
#pragma unroll
      for (int off = 32; off > 0; off >>= 1) s += __shfl_down(s, off);
      if (tx == 0) pred[gn] = 1.f / (1.f + expf(-(s + bfc[0])));
    } else {
      out[gn * D_GNN + d0] = acc0[i];
      out[gn * D_GNN + d1] = acc1[i];
    }
  }
}

// ---------------------------------------------------------------------------
// CSR build: degree count -> exclusive scan -> slot fill
// ---------------------------------------------------------------------------
__global__ __launch_bounds__(256) void deg_kernel(const int* __restrict__ ei,
                                                  int* __restrict__ deg) {
  int e = blockIdx.x * 256 + threadIdx.x;
  if (e < N_EDGES) atomicAdd(&deg[ei[N_EDGES + e]], 1);
}

__global__ __launch_bounds__(1024) void scan_kernel(const int* __restrict__ deg,
                                                    int* __restrict__ rowptr) {
  __shared__ int sums[1024];
  const int t = threadIdx.x;
  const int per = (N_NODES + 1023) / 1024;  // 49
  const int base = t * per;
  int s = 0;
  for (int i = 0; i < per; i++) {
    int idx = base + i;
    if (idx < N_NODES) s += deg[idx];
  }
  sums[t] = s;
  __syncthreads();
  for (int off = 1; off < 1024; off <<= 1) {
    int v = (t >= off) ? sums[t - off] : 0;
    __syncthreads();
    sums[t] += v;
    __syncthreads();
  }
  int run = (t == 0) ? 0 : sums[t - 1];  // exclusive prefix for this thread
  for (int i = 0; i < per; i++) {
    int idx = base + i;
    if (idx < N_NODES) {
      rowptr[idx] = run;
      run += deg[idx];
    } else if (idx == N_NODES) {
      rowptr[idx] = run;
    }
  }
}

__global__ __launch_bounds__(256) void fill_kernel(const int* __restrict__ ei,
                                                   const int* __restrict__ rowptr,
                                                   int* __restrict__ cursor,
                                                   int* __restrict__ col) {
  int e = blockIdx.x * 256 + threadIdx.x;
  if (e >= N_EDGES) return;
  int dst = ei[N_EDGES + e];
  int pos = atomicAdd(&cursor[dst], 1);
  col[rowptr[dst] + pos] = ei[e];  // src
}

// ---------------------------------------------------------------------------
// Gather: one wave per node. 64 lanes x float2 = full 128-dim row per
// neighbor (coalesced 512B read of y[src]). col indices loaded once per 64
// neighbors, broadcast via shuffle. Writes mean directly (no atomics).
// ---------------------------------------------------------------------------
__global__ __launch_bounds__(256) void gather_kernel(
    const int* __restrict__ rowptr, const int* __restrict__ col,
    const float* __restrict__ y, float* __restrict__ mean_out) {
  const int node = (blockIdx.x * 256 + threadIdx.x) >> 6;
  const int lane = threadIdx.x & 63;
  if (node >= N_NODES) return;
  const int b = rowptr[node], e = rowptr[node + 1];
  float ax = 0.f, ay = 0.f;
  for (int i = b; i < e; i += 64) {
    int c = (i + lane < e) ? col[i + lane] : 0;  // coalesced batch of indices
    int m = min(64, e - i);
    int j = 0;
    for (; j + 4 <= m; j += 4) {
      int s0 = __shfl(c, j), s1 = __shfl(c, j + 1);
      int s2 = __shfl(c, j + 2), s3 = __shfl(c, j + 3);
      float2 v0 = ((const float2*)y)[(size_t)s0 * 64 + lane];
      float2 v1 = ((const float2*)y)[(size_t)s1 * 64 + lane];
      float2 v2 = ((const float2*)y)[(size_t)s2 * 64 + lane];
      float2 v3 = ((const float2*)y)[(size_t)s3 * 64 + lane];
      ax += (v0.x + v1.x) + (v2.x + v3.x);
      ay += (v0.y + v1.y) + (v2.y + v3.y);
    }
    for (; j < m; j++) {
      int s0 = __shfl(c, j);
      float2 v0 = ((const float2*)y)[(size_t)s0 * 64 + lane];
      ax += v0.x;
      ay += v0.y;
    }
  }
  const int deg = e - b;
  const float ic = deg > 0 ? 1.f / (float)deg : 0.f;
  float2 r;
  r.x = ax * ic;
  r.y = ay * ic;
  ((float2*)mean_out)[(size_t)node * 64 + lane] = r;
}

extern "C" void kernel_launch(void* const* d_in, const int* in_sizes, int n_in,
                              void* d_out, int out_size, void* d_ws,
                              size_t ws_size, hipStream_t stream) {
  const float* x   = (const float*)d_in[0];
  const int*   ei  = (const int*)d_in[1];
  const float* Wl  = (const float*)d_in[2];
  const float* bl  = (const float*)d_in[3];
  const float* Wr  = (const float*)d_in[4];
  const float* Wfc = (const float*)d_in[5];
  const float* bfc = (const float*)d_in[6];

  float* out  = (float*)d_out;
  float* h    = out;                        // [N,128]; holds mean then final h
  float* pred = out + (size_t)N_NODES * D_GNN;

  float* y      = (float*)d_ws;             // [N,128] projected features
  int*   rowptr = (int*)(y + (size_t)N_NODES * D_GNN);  // [N+1]
  int*   tmp    = rowptr + (N_NODES + 1);   // [N] deg, reused as cursor
  int*   col    = tmp + N_NODES;            // [E]

  // --- CSR build (only int atomics on 50K counters) ---
  hipMemsetAsync(tmp, 0, N_NODES * sizeof(int), stream);
  deg_kernel<<<(N_EDGES + 255) / 256, 256, 0, stream>>>(ei, tmp);
  scan_kernel<<<1, 1024, 0, stream>>>(tmp, rowptr);
  hipMemsetAsync(tmp, 0, N_NODES * sizeof(int), stream);
  fill_kernel<<<(N_EDGES + 255) / 256, 256, 0, stream>>>(ei, rowptr, tmp, col);

  // --- projection y = x @ W_l ---
  const int gemm_blocks = (N_NODES + 31) / 32;  // 1563
  gemm_kernel<false><<<gemm_blocks, 256, 0, stream>>>(x, Wl, y, nullptr,
                                                      nullptr, nullptr, nullptr);

  // --- mean aggregation (gather, no atomics) -> h ---
  gather_kernel<<<(N_NODES * 64 + 255) / 256, 256, 0, stream>>>(rowptr, col, y, h);

  // --- h = mean + b_l + x @ W_r, fused pred epilogue ---
  gemm_kernel<true><<<gemm_blocks, 256, 0, stream>>>(x, Wr, h, bl, Wfc, bfc, pred);
}

// Round 3
// 337.436 us; speedup vs baseline: 3.8726x; 1.3681x over previous
//
#include <hip/hip_runtime.h>
#include <math.h>

#define N_NODES 50000
#define N_EDGES 600000
#define D_IN 256
#define D_GNN 128

typedef short s16x8 __attribute__((ext_vector_type(8)));
typedef float f32x4 __attribute__((ext_vector_type(4)));

__device__ __forceinline__ unsigned short f2bf(float f) {
  unsigned int u = __float_as_uint(f);
  u += 0x7FFFu + ((u >> 16) & 1u);  // RNE
  return (unsigned short)(u >> 16);
}

// ---------------------------------------------------------------------------
// x (f32 [N,256]) -> xb (bf16 [N,256]); float4 in, ushort4 out
// ---------------------------------------------------------------------------
__global__ __launch_bounds__(256) void convert_x(const float* __restrict__ x,
                                                 ushort* __restrict__ xb) {
  int i = blockIdx.x * 256 + threadIdx.x;  // one per 4 elements
  if (i >= N_NODES * 64) return;
  float4 v = ((const float4*)x)[i];
  ushort4 o;
  o.x = f2bf(v.x); o.y = f2bf(v.y); o.z = f2bf(v.z); o.w = f2bf(v.w);
  ((ushort4*)xb)[i] = o;
}

// ---------------------------------------------------------------------------
// Pack Wc = [W_l | W_r] (256 k x 256 cols) into B-fragment order, bf16:
// Wcp[((ks*256 + col)*4 + q)*8 + j] = Wc[ks*32 + q*8 + j][col]
// so a lane's 8 B-elements (k = q*8..q*8+7 at fixed col) are one 16B load.
// ---------------------------------------------------------------------------
__global__ __launch_bounds__(256) void pack_w(const float* __restrict__ Wl,
                                              const float* __restrict__ Wr,
                                              ushort* __restrict__ Wcp) {
  int i = blockIdx.x * 256 + threadIdx.x;  // [0, 8*256*4)
  if (i >= 8192) return;
  int q = i & 3, col = (i >> 2) & 255, ks = i >> 10;
  const float* W = (col < 128) ? Wl : Wr;
  int c = col & 127;
  int k0 = ks * 32 + q * 8;
  ushort tmp[8];
#pragma unroll
  for (int j = 0; j < 8; j++) tmp[j] = f2bf(W[(k0 + j) * D_GNN + c]);
  s16x8 v;
#pragma unroll
  for (int j = 0; j < 8; j++) v[j] = (short)tmp[j];
  *((s16x8*)(Wcp + (size_t)i * 8)) = v;
}

// ---------------------------------------------------------------------------
// MFMA GEMM: out = xb @ Wc. Block = 128 nodes x 128 cols, 4 waves (2x2),
// wave = 64x64 as 4x4 grid of 16x16x32 bf16 MFMA tiles, K=256 (8 steps).
// A and B fragments loaded directly from global (no LDS): A = 16B contiguous
// in xb row; B = 16B from pre-packed Wcp (128KB, L2-resident).
// blockIdx.y==0 -> y_l (store bf16 for gather); ==1 -> y_r + b_l (f32, into h)
// ---------------------------------------------------------------------------
__global__ __launch_bounds__(256) void mfma_gemm(
    const ushort* __restrict__ xb, const ushort* __restrict__ Wcp,
    const float* __restrict__ b_l, ushort* __restrict__ yb,
    float* __restrict__ yr) {
  const int t = threadIdx.x;
  const int l = t & 63;
  const int w = t >> 6;
  const int wrow = w & 1, wcol = w >> 1;
  const int nodeBase = blockIdx.x * 128 + wrow * 64;
  const int cb = blockIdx.y;
  const int c2base = wcol * 64;
  const int lq = l >> 4;    // quad (0..3)
  const int l16 = l & 15;

  f32x4 acc[4][4];
#pragma unroll
  for (int a = 0; a < 4; a++)
#pragma unroll
    for (int b = 0; b < 4; b++) acc[a][b] = (f32x4){0.f, 0.f, 0.f, 0.f};

  int arow[4];
#pragma unroll
  for (int nt = 0; nt < 4; nt++) {
    int r = nodeBase + nt * 16 + l16;
    arow[nt] = (r < N_NODES) ? r : (N_NODES - 1);  // clamp; stores guarded
  }

  for (int ks = 0; ks < 8; ks++) {
    const int ka = ks * 32 + lq * 8;
    s16x8 A[4], B[4];
#pragma unroll
    for (int nt = 0; nt < 4; nt++)
      A[nt] = *((const s16x8*)(xb + (size_t)arow[nt] * 256 + ka));
#pragma unroll
    for (int ct = 0; ct < 4; ct++) {
      int col = cb * 128 + c2base + ct * 16 + l16;
      B[ct] = *((const s16x8*)(Wcp + ((size_t)(ks * 256 + col) * 4 + lq) * 8));
    }
#pragma unroll
    for (int nt = 0; nt < 4; nt++)
#pragma unroll
      for (int ct = 0; ct < 4; ct++)
        acc[nt][ct] = __builtin_amdgcn_mfma_f32_16x16x32_bf16(
            A[nt], B[ct], acc[nt][ct], 0, 0, 0);
  }

  // C/D layout: col = lane&15, row = (lane>>4)*4 + reg  [m89/m91-verified]
#pragma unroll
  for (int nt = 0; nt < 4; nt++) {
#pragma unroll
    for (int ct = 0; ct < 4; ct++) {
      int c2 = c2base + ct * 16 + l16;
#pragma unroll
      for (int r = 0; r < 4; r++) {
        int node = nodeBase + nt * 16 + lq * 4 + r;
        if (node < N_NODES) {
          if (cb == 0)
            yb[(size_t)node * D_GNN + c2] = f2bf(acc[nt][ct][r]);
          else
            yr[(size_t)node * D_GNN + c2] = acc[nt][ct][r] + b_l[c2];
        }
      }
    }
  }
}

// ---------------------------------------------------------------------------
// CSR build: degree count -> exclusive scan -> slot fill
// ---------------------------------------------------------------------------
__global__ __launch_bounds__(256) void deg_kernel(const int* __restrict__ ei,
                                                  int* __restrict__ deg) {
  int e = blockIdx.x * 256 + threadIdx.x;
  if (e < N_EDGES) atomicAdd(&deg[ei[N_EDGES + e]], 1);
}

__global__ __launch_bounds__(1024) void scan_kernel(const int* __restrict__ deg,
                                                    int* __restrict__ rowptr) {
  __shared__ int sums[1024];
  const int t = threadIdx.x;
  const int per = (N_NODES + 1023) / 1024;  // 49
  const int base = t * per;
  int s = 0;
  for (int i = 0; i < per; i++) {
    int idx = base + i;
    if (idx < N_NODES) s += deg[idx];
  }
  sums[t] = s;
  __syncthreads();
  for (int off = 1; off < 1024; off <<= 1) {
    int v = (t >= off) ? sums[t - off] : 0;
    __syncthreads();
    sums[t] += v;
    __syncthreads();
  }
  int run = (t == 0) ? 0 : sums[t - 1];
  for (int i = 0; i < per; i++) {
    int idx = base + i;
    if (idx < N_NODES) {
      rowptr[idx] = run;
      run += deg[idx];
    } else if (idx == N_NODES) {
      rowptr[idx] = run;
    }
  }
}

__global__ __launch_bounds__(256) void fill_kernel(const int* __restrict__ ei,
                                                   const int* __restrict__ rowptr,
                                                   int* __restrict__ cursor,
                                                   int* __restrict__ col) {
  int e = blockIdx.x * 256 + threadIdx.x;
  if (e >= N_EDGES) return;
  int dst = ei[N_EDGES + e];
  int pos = atomicAdd(&cursor[dst], 1);
  col[rowptr[dst] + pos] = ei[e];  // src
}

// ---------------------------------------------------------------------------
// Gather + epilogue + pred head. One wave per node; lane owns dims
// {2*lane, 2*lane+1}. Reads bf16 y_l rows (256B each, L2/L3-resident),
// means, adds y_r (+bias, already in h), writes h, reduces pred.
// ---------------------------------------------------------------------------
__global__ __launch_bounds__(256) void gather_pred(
    const int* __restrict__ rowptr, const int* __restrict__ col,
    const ushort* __restrict__ yb, const float* __restrict__ Wfc,
    const float* __restrict__ bfc, float* __restrict__ h,
    float* __restrict__ pred) {
  const int node = (blockIdx.x * 256 + threadIdx.x) >> 6;
  const int lane = threadIdx.x & 63;
  if (node >= N_NODES) return;
  const int b = rowptr[node], e = rowptr[node + 1];
  float ax = 0.f, ay = 0.f;
  const unsigned int* y32 = (const unsigned int*)yb;
  for (int i = b; i < e; i += 64) {
    int c = (i + lane < e) ? col[i + lane] : 0;
    int m = min(64, e - i);
    int j = 0;
    for (; j + 4 <= m; j += 4) {
      int s0 = __shfl(c, j), s1 = __shfl(c, j + 1);
      int s2 = __shfl(c, j + 2), s3 = __shfl(c, j + 3);
      unsigned int v0 = y32[(size_t)s0 * 64 + lane];
      unsigned int v1 = y32[(size_t)s1 * 64 + lane];
      unsigned int v2 = y32[(size_t)s2 * 64 + lane];
      unsigned int v3 = y32[(size_t)s3 * 64 + lane];
      ax += __uint_as_float(v0 << 16) + __uint_as_float(v1 << 16) +
            __uint_as_float(v2 << 16) + __uint_as_float(v3 << 16);
      ay += __uint_as_float(v0 & 0xFFFF0000u) + __uint_as_float(v1 & 0xFFFF0000u) +
            __uint_as_float(v2 & 0xFFFF0000u) + __uint_as_float(v3 & 0xFFFF0000u);
    }
    for (; j < m; j++) {
      int s0 = __shfl(c, j);
      unsigned int v0 = y32[(size_t)s0 * 64 + lane];
      ax += __uint_as_float(v0 << 16);
      ay += __uint_as_float(v0 & 0xFFFF0000u);
    }
  }
  const int deg = e - b;
  const float ic = deg > 0 ? 1.f / (float)deg : 0.f;
  float2 yr2 = ((const float2*)h)[(size_t)node * 64 + lane];
  float h0 = ax * ic + yr2.x;
  float h1 = ay * ic + yr2.y;
  float2 hv; hv.x = h0; hv.y = h1;
  ((float2*)h)[(size_t)node * 64 + lane] = hv;
  float s = h0 * Wfc[2 * lane] + h1 * Wfc[2 * lane + 1];
#pragma unroll
  for (int off = 32; off > 0; off >>= 1) s += __shfl_down(s, off);
  if (lane == 0) pred[node] = 1.f / (1.f + expf(-(s + bfc[0])));
}

extern "C" void kernel_launch(void* const* d_in, const int* in_sizes, int n_in,
                              void* d_out, int out_size, void* d_ws,
                              size_t ws_size, hipStream_t stream) {
  const float* x   = (const float*)d_in[0];
  const int*   ei  = (const int*)d_in[1];
  const float* Wl  = (const float*)d_in[2];
  const float* bl  = (const float*)d_in[3];
  const float* Wr  = (const float*)d_in[4];
  const float* Wfc = (const float*)d_in[5];
  const float* bfc = (const float*)d_in[6];

  float* out  = (float*)d_out;
  float* h    = out;                        // [N,128]; y_r+bias then final h
  float* pred = out + (size_t)N_NODES * D_GNN;

  ushort* xb   = (ushort*)d_ws;                               // [N,256] bf16
  ushort* Wcp  = xb + (size_t)N_NODES * D_IN;                 // 8192*8 bf16
  ushort* yb   = Wcp + 8192 * 8;                              // [N,128] bf16
  int* rowptr  = (int*)(yb + (size_t)N_NODES * D_GNN);        // [N+1]
  int* tmp     = rowptr + (N_NODES + 1);                      // [N]
  int* col     = tmp + N_NODES;                               // [E]

  // --- CSR build ---
  hipMemsetAsync(tmp, 0, N_NODES * sizeof(int), stream);
  deg_kernel<<<(N_EDGES + 255) / 256, 256, 0, stream>>>(ei, tmp);
  scan_kernel<<<1, 1024, 0, stream>>>(tmp, rowptr);
  hipMemsetAsync(tmp, 0, N_NODES * sizeof(int), stream);
  fill_kernel<<<(N_EDGES + 255) / 256, 256, 0, stream>>>(ei, rowptr, tmp, col);

  // --- bf16 conversion + weight packing ---
  convert_x<<<(N_NODES * 64 + 255) / 256, 256, 0, stream>>>(x, xb);
  pack_w<<<32, 256, 0, stream>>>(Wl, Wr, Wcp);

  // --- y_l = x@W_l (bf16 out), y_r = x@W_r + b_l (f32, into h region) ---
  dim3 ggrid((N_NODES + 127) / 128, 2);
  mfma_gemm<<<ggrid, 256, 0, stream>>>(xb, Wcp, bl, yb, h);

  // --- mean gather + h epilogue + pred head ---
  gather_pred<<<(N_NODES * 64 + 255) / 256, 256, 0, stream>>>(
      rowptr, col, yb, Wfc, bfc, h, pred);
}

// Round 4
// 247.813 us; speedup vs baseline: 5.2731x; 1.3617x over previous
//
#include <hip/hip_runtime.h>
#include <math.h>

#define N_NODES 50000
#define N_EDGES 600000
#define D_IN 256
#define D_GNN 128
#define SCAN_BLOCKS ((N_NODES + 255) / 256)  // 196

typedef short s16x8 __attribute__((ext_vector_type(8)));
typedef float f32x4 __attribute__((ext_vector_type(4)));

__device__ __forceinline__ unsigned short f2bf(float f) {
  unsigned int u = __float_as_uint(f);
  u += 0x7FFFu + ((u >> 16) & 1u);  // RNE
  return (unsigned short)(u >> 16);
}

// ---------------------------------------------------------------------------
// x (f32 [N,256]) -> xb (bf16 [N,256]); float4 in, ushort4 out
// ---------------------------------------------------------------------------
__global__ __launch_bounds__(256) void convert_x(const float* __restrict__ x,
                                                 ushort* __restrict__ xb) {
  int i = blockIdx.x * 256 + threadIdx.x;  // one per 4 elements
  if (i >= N_NODES * 64) return;
  float4 v = ((const float4*)x)[i];
  ushort4 o;
  o.x = f2bf(v.x); o.y = f2bf(v.y); o.z = f2bf(v.z); o.w = f2bf(v.w);
  ((ushort4*)xb)[i] = o;
}

// ---------------------------------------------------------------------------
// Pack Wc = [W_l | W_r] (256 k x 256 cols) into B-fragment order, bf16.
// ---------------------------------------------------------------------------
__global__ __launch_bounds__(256) void pack_w(const float* __restrict__ Wl,
                                              const float* __restrict__ Wr,
                                              ushort* __restrict__ Wcp) {
  int i = blockIdx.x * 256 + threadIdx.x;  // [0, 8*256*4)
  if (i >= 8192) return;
  int q = i & 3, col = (i >> 2) & 255, ks = i >> 10;
  const float* W = (col < 128) ? Wl : Wr;
  int c = col & 127;
  int k0 = ks * 32 + q * 8;
  ushort tmp[8];
#pragma unroll
  for (int j = 0; j < 8; j++) tmp[j] = f2bf(W[(k0 + j) * D_GNN + c]);
  s16x8 v;
#pragma unroll
  for (int j = 0; j < 8; j++) v[j] = (short)tmp[j];
  *((s16x8*)(Wcp + (size_t)i * 8)) = v;
}

// ---------------------------------------------------------------------------
// MFMA GEMM: out = xb @ [W_l|W_r]. Block = 128 nodes x 128 cols, 4 waves.
// ---------------------------------------------------------------------------
__global__ __launch_bounds__(256) void mfma_gemm(
    const ushort* __restrict__ xb, const ushort* __restrict__ Wcp,
    const float* __restrict__ b_l, ushort* __restrict__ yb,
    float* __restrict__ yr) {
  const int t = threadIdx.x;
  const int l = t & 63;
  const int w = t >> 6;
  const int wrow = w & 1, wcol = w >> 1;
  const int nodeBase = blockIdx.x * 128 + wrow * 64;
  const int cb = blockIdx.y;
  const int c2base = wcol * 64;
  const int lq = l >> 4;
  const int l16 = l & 15;

  f32x4 acc[4][4];
#pragma unroll
  for (int a = 0; a < 4; a++)
#pragma unroll
    for (int b = 0; b < 4; b++) acc[a][b] = (f32x4){0.f, 0.f, 0.f, 0.f};

  int arow[4];
#pragma unroll
  for (int nt = 0; nt < 4; nt++) {
    int r = nodeBase + nt * 16 + l16;
    arow[nt] = (r < N_NODES) ? r : (N_NODES - 1);
  }

  for (int ks = 0; ks < 8; ks++) {
    const int ka = ks * 32 + lq * 8;
    s16x8 A[4], B[4];
#pragma unroll
    for (int nt = 0; nt < 4; nt++)
      A[nt] = *((const s16x8*)(xb + (size_t)arow[nt] * 256 + ka));
#pragma unroll
    for (int ct = 0; ct < 4; ct++) {
      int col = cb * 128 + c2base + ct * 16 + l16;
      B[ct] = *((const s16x8*)(Wcp + ((size_t)(ks * 256 + col) * 4 + lq) * 8));
    }
#pragma unroll
    for (int nt = 0; nt < 4; nt++)
#pragma unroll
      for (int ct = 0; ct < 4; ct++)
        acc[nt][ct] = __builtin_amdgcn_mfma_f32_16x16x32_bf16(
            A[nt], B[ct], acc[nt][ct], 0, 0, 0);
  }

#pragma unroll
  for (int nt = 0; nt < 4; nt++) {
#pragma unroll
    for (int ct = 0; ct < 4; ct++) {
      int c2 = c2base + ct * 16 + l16;
#pragma unroll
      for (int r = 0; r < 4; r++) {
        int node = nodeBase + nt * 16 + lq * 4 + r;
        if (node < N_NODES) {
          if (cb == 0)
            yb[(size_t)node * D_GNN + c2] = f2bf(acc[nt][ct][r]);
          else
            yr[(size_t)node * D_GNN + c2] = acc[nt][ct][r] + b_l[c2];
        }
      }
    }
  }
}

// ---------------------------------------------------------------------------
// CSR build: degree count -> 3-stage parallel exclusive scan -> slot fill
// ---------------------------------------------------------------------------
__global__ __launch_bounds__(256) void deg_kernel(const int* __restrict__ ei,
                                                  int* __restrict__ deg) {
  int e = blockIdx.x * 256 + threadIdx.x;
  if (e < N_EDGES) atomicAdd(&deg[ei[N_EDGES + e]], 1);
}

// Stage 1: per-block exclusive scan of deg (256/block), emit block sums.
__global__ __launch_bounds__(256) void partial_scan(
    const int* __restrict__ deg, int* __restrict__ rowptr,
    int* __restrict__ blockSums) {
  __shared__ int s[256];
  const int t = threadIdx.x;
  const int n = blockIdx.x * 256 + t;
  int d = (n < N_NODES) ? deg[n] : 0;
  s[t] = d;
  __syncthreads();
#pragma unroll
  for (int off = 1; off < 256; off <<= 1) {
    int v = (t >= off) ? s[t - off] : 0;
    __syncthreads();
    s[t] += v;
    __syncthreads();
  }
  if (n < N_NODES) rowptr[n] = s[t] - d;  // exclusive local prefix
  if (t == 255) blockSums[blockIdx.x] = s[255];
}

// Stage 2: single block scans the block sums -> exclusive block offsets.
__global__ __launch_bounds__(256) void scan_sums(int* __restrict__ blockSums,
                                                 int* __restrict__ blockOff) {
  __shared__ int s[256];
  const int t = threadIdx.x;
  int d = (t < SCAN_BLOCKS) ? blockSums[t] : 0;
  s[t] = d;
  __syncthreads();
#pragma unroll
  for (int off = 1; off < 256; off <<= 1) {
    int v = (t >= off) ? s[t - off] : 0;
    __syncthreads();
    s[t] += v;
    __syncthreads();
  }
  if (t < SCAN_BLOCKS) blockOff[t] = s[t] - d;
}

// Stage 3: add block offsets; rowptr[N] is the compile-time edge count.
__global__ __launch_bounds__(256) void add_off(int* __restrict__ rowptr,
                                               const int* __restrict__ blockOff) {
  const int n = blockIdx.x * 256 + threadIdx.x;
  if (n < N_NODES) rowptr[n] += blockOff[blockIdx.x];
  if (n == 0) rowptr[N_NODES] = N_EDGES;
}

__global__ __launch_bounds__(256) void fill_kernel(const int* __restrict__ ei,
                                                   const int* __restrict__ rowptr,
                                                   int* __restrict__ cursor,
                                                   int* __restrict__ col) {
  int e = blockIdx.x * 256 + threadIdx.x;
  if (e >= N_EDGES) return;
  int dst = ei[N_EDGES + e];
  int pos = atomicAdd(&cursor[dst], 1);
  col[rowptr[dst] + pos] = ei[e];  // src
}

// ---------------------------------------------------------------------------
// Gather + epilogue + pred head. One wave per node.
// ---------------------------------------------------------------------------
__global__ __launch_bounds__(256) void gather_pred(
    const int* __restrict__ rowptr, const int* __restrict__ col,
    const ushort* __restrict__ yb, const float* __restrict__ Wfc,
    const float* __restrict__ bfc, float* __restrict__ h,
    float* __restrict__ pred) {
  const int node = (blockIdx.x * 256 + threadIdx.x) >> 6;
  const int lane = threadIdx.x & 63;
  if (node >= N_NODES) return;
  const int b = rowptr[node], e = rowptr[node + 1];
  float ax = 0.f, ay = 0.f;
  const unsigned int* y32 = (const unsigned int*)yb;
  for (int i = b; i < e; i += 64) {
    int c = (i + lane < e) ? col[i + lane] : 0;
    int m = min(64, e - i);
    int j = 0;
    for (; j + 4 <= m; j += 4) {
      int s0 = __shfl(c, j), s1 = __shfl(c, j + 1);
      int s2 = __shfl(c, j + 2), s3 = __shfl(c, j + 3);
      unsigned int v0 = y32[(size_t)s0 * 64 + lane];
      unsigned int v1 = y32[(size_t)s1 * 64 + lane];
      unsigned int v2 = y32[(size_t)s2 * 64 + lane];
      unsigned int v3 = y32[(size_t)s3 * 64 + lane];
      ax += __uint_as_float(v0 << 16) + __uint_as_float(v1 << 16) +
            __uint_as_float(v2 << 16) + __uint_as_float(v3 << 16);
      ay += __uint_as_float(v0 & 0xFFFF0000u) + __uint_as_float(v1 & 0xFFFF0000u) +
            __uint_as_float(v2 & 0xFFFF0000u) + __uint_as_float(v3 & 0xFFFF0000u);
    }
    for (; j < m; j++) {
      int s0 = __shfl(c, j);
      unsigned int v0 = y32[(size_t)s0 * 64 + lane];
      ax += __uint_as_float(v0 << 16);
      ay += __uint_as_float(v0 & 0xFFFF0000u);
    }
  }
  const int deg = e - b;
  const float ic = deg > 0 ? 1.f / (float)deg : 0.f;
  float2 yr2 = ((const float2*)h)[(size_t)node * 64 + lane];
  float h0 = ax * ic + yr2.x;
  float h1 = ay * ic + yr2.y;
  float2 hv; hv.x = h0; hv.y = h1;
  ((float2*)h)[(size_t)node * 64 + lane] = hv;
  float s = h0 * Wfc[2 * lane] + h1 * Wfc[2 * lane + 1];
#pragma unroll
  for (int off = 32; off > 0; off >>= 1) s += __shfl_down(s, off);
  if (lane == 0) pred[node] = 1.f / (1.f + expf(-(s + bfc[0])));
}

extern "C" void kernel_launch(void* const* d_in, const int* in_sizes, int n_in,
                              void* d_out, int out_size, void* d_ws,
                              size_t ws_size, hipStream_t stream) {
  const float* x   = (const float*)d_in[0];
  const int*   ei  = (const int*)d_in[1];
  const float* Wl  = (const float*)d_in[2];
  const float* bl  = (const float*)d_in[3];
  const float* Wr  = (const float*)d_in[4];
  const float* Wfc = (const float*)d_in[5];
  const float* bfc = (const float*)d_in[6];

  float* out  = (float*)d_out;
  float* h    = out;                        // [N,128]; y_r+bias then final h
  float* pred = out + (size_t)N_NODES * D_GNN;

  ushort* xb   = (ushort*)d_ws;                               // [N,256] bf16
  ushort* Wcp  = xb + (size_t)N_NODES * D_IN;                 // 8192*8 bf16
  ushort* yb   = Wcp + 8192 * 8;                              // [N,128] bf16
  int* rowptr  = (int*)(yb + (size_t)N_NODES * D_GNN);        // [N+1]
  int* tmp     = rowptr + (N_NODES + 1);                      // [N]
  int* col     = tmp + N_NODES;                               // [E]
  int* bsums   = col + N_EDGES;                               // [256]
  int* boff    = bsums + 256;                                 // [256]

  // --- CSR build ---
  hipMemsetAsync(tmp, 0, N_NODES * sizeof(int), stream);
  deg_kernel<<<(N_EDGES + 255) / 256, 256, 0, stream>>>(ei, tmp);
  partial_scan<<<SCAN_BLOCKS, 256, 0, stream>>>(tmp, rowptr, bsums);
  scan_sums<<<1, 256, 0, stream>>>(bsums, boff);
  add_off<<<SCAN_BLOCKS, 256, 0, stream>>>(rowptr, boff);
  hipMemsetAsync(tmp, 0, N_NODES * sizeof(int), stream);
  fill_kernel<<<(N_EDGES + 255) / 256, 256, 0, stream>>>(ei, rowptr, tmp, col);

  // --- bf16 conversion + weight packing ---
  convert_x<<<(N_NODES * 64 + 255) / 256, 256, 0, stream>>>(x, xb);
  pack_w<<<32, 256, 0, stream>>>(Wl, Wr, Wcp);

  // --- y_l = x@W_l (bf16 out), y_r = x@W_r + b_l (f32, into h region) ---
  dim3 ggrid((N_NODES + 127) / 128, 2);
  mfma_gemm<<<ggrid, 256, 0, stream>>>(xb, Wcp, bl, yb, h);

  // --- mean gather + h epilogue + pred head ---
  gather_pred<<<(N_NODES * 64 + 255) / 256, 256, 0, stream>>>(
      rowptr, col, yb, Wfc, bfc, h, pred);
}